// Round 5
// baseline (369.764 us; speedup 1.0000x reference)
//
#include <hip/hip_runtime.h>

#define M_ROWS 16384
#define N_CODES 8192
#define K_DIM   256
#define NSPLIT  64        // code-tile splits (N/128)
#define CAP     16384
#define TAU     0.05f
#define RSTRIDE 8

typedef _Float16 half8 __attribute__((ext_vector_type(8)));
typedef float floatx16 __attribute__((ext_vector_type(16)));

#define GLL16(g, l) __builtin_amdgcn_global_load_lds(                         \
    (const __attribute__((address_space(1))) void*)(g),                       \
    (__attribute__((address_space(3))) void*)(l), 16, 0, 0)

#define MFMA16(a, b, c) __builtin_amdgcn_mfma_f32_32x32x16_f16(a, b, c, 0, 0, 0)
#define SCB __builtin_amdgcn_sched_barrier(0)

// ---- pack codebook into fragment-ordered fp16 h+l blobs ----
// blob per (code-tile 128, kc of 32): 8192 fp16 = [it4][pl2][ks2][lh2][rr32][j8]
__global__ void pack_cb(const float* __restrict__ in, _Float16* __restrict__ out) {
  const int t = blockIdx.x * 256 + threadIdx.x;
  const int C = t >> 5, G = t & 31;
  const int ct = C >> 7, r = C & 127, it = r >> 5, rr = r & 31;
  const int kc = G >> 2, g2 = G & 3, ks = g2 >> 1, lh = g2 & 1;
  const float* src = in + (size_t)C * K_DIM + G * 8;
  half8 hv, lv;
#pragma unroll
  for (int j = 0; j < 8; ++j) {
    const float v = src[j];
    const _Float16 h = (_Float16)v;
    hv[j] = h;
    lv[j] = (_Float16)(v - (float)h);
  }
  _Float16* blob = out + ((size_t)ct * 8 + kc) * 8192;
  const int offh = ((((it * 2 + 0) * 2 + ks) * 2 + lh) * 32 + rr) * 8;
  const int offl = ((((it * 2 + 1) * 2 + ks) * 2 + lh) * 32 + rr) * 8;
  *reinterpret_cast<half8*>(blob + offh) = hv;
  *reinterpret_cast<half8*>(blob + offl) = lv;
}

// ---- pack x into fragment-ordered fp16 h-only blobs ----
// blob per (row-tile 128, kc of 32): 4096 fp16 = [jt4][ks2][lh2][rr32][j8]
__global__ void pack_x(const float* __restrict__ in, _Float16* __restrict__ out) {
  const int t = blockIdx.x * 256 + threadIdx.x;
  const int R = t >> 5, G = t & 31;
  const int bx = R >> 7, r = R & 127, jt = r >> 5, rr = r & 31;
  const int kc = G >> 2, g2 = G & 3, ks = g2 >> 1, lh = g2 & 1;
  const float* src = in + (size_t)R * K_DIM + G * 8;
  half8 hv;
#pragma unroll
  for (int j = 0; j < 8; ++j) hv[j] = (_Float16)src[j];
  _Float16* blob = out + ((size_t)bx * 8 + kc) * 4096;
  const int off = (((jt * 2 + ks) * 2 + lh) * 32 + rr) * 8;
  *reinterpret_cast<half8*>(blob + off) = hv;
}

// ---- en2[c] = 0.5*||e_c||^2 (exact fp32); zeroes risky counter ----
__global__ void enorm_k(const float* __restrict__ cb, float* __restrict__ en2,
                        int* __restrict__ cnt) {
  if (blockIdx.x == 0 && threadIdx.x == 0) *cnt = 0;
  const int row = blockIdx.x * 4 + (threadIdx.x >> 6);
  const int lane = threadIdx.x & 63;
  const float4 v = *reinterpret_cast<const float4*>(cb + (size_t)row * K_DIM + lane * 4);
  float s = v.x * v.x + v.y * v.y + v.z * v.z + v.w * v.w;
#pragma unroll
  for (int o = 32; o > 0; o >>= 1) s += __shfl_down(s, o, 64);
  if (lane == 0) en2[row] = 0.5f * s;
}

// ---- fused 2-product split-f16 MFMA distance, 128x128 tile, ct=1 per block ----
#define STAGE(buf, kcv)                                                     \
  {                                                                         \
    const _Float16* ga_ = gA + (size_t)(kcv) * 8192;                        \
    const _Float16* gb_ = gB + (size_t)(kcv) * 4096;                        \
    _Pragma("unroll")                                                       \
    for (int q = 0; q < 4; ++q)                                             \
      GLL16(ga_ + q * 2048 + tid * 8, ldsA + (buf) * 8192 + q * 2048 + tid * 8); \
    _Pragma("unroll")                                                       \
    for (int q = 0; q < 2; ++q)                                             \
      GLL16(gb_ + q * 2048 + tid * 8, ldsB + (buf) * 4096 + q * 2048 + tid * 8); \
  }

__global__ __launch_bounds__(256, 3)
void vq_dist(const _Float16* __restrict__ Apack, const _Float16* __restrict__ Bpack,
             const float* __restrict__ en2, float* __restrict__ candV,
             int* __restrict__ candI, float* __restrict__ cand2) {
  __shared__ _Float16 ldsA[2 * 8192];   // 32KB dbuf A (codes, h+l)
  __shared__ _Float16 ldsB[2 * 4096];   // 16KB dbuf B (x, h)

  const int tid = threadIdx.x;
  const int wv = tid >> 6, lane = tid & 63;
  const int wm = wv >> 1, wn = wv & 1;
  const int l31 = lane & 31, lh = lane >> 5;

  // XCD-grouped 2D swizzle: each XCD gets 32 bx x 32 ct
  const int lid = blockIdx.x;
  const int xcd = lid & 7, w = lid >> 3;
  const int bx = (xcd & 3) * 32 + (w & 31);
  const int ct = (xcd >> 2) * 32 + (w >> 5);

  const _Float16* gA = Apack + (size_t)ct * 8 * 8192;
  const _Float16* gB = Bpack + (size_t)bx * 8 * 4096;

  floatx16 acc[2][2] = {};

  STAGE(0, 0);

#pragma unroll
  for (int kc = 0; kc < 8; ++kc) {
    const int bo = (kc & 1) * 8192;
    const int bob = (kc & 1) * 4096;
    if (kc < 7) {
      STAGE((kc + 1) & 1, kc + 1);
      asm volatile("s_waitcnt vmcnt(6)" ::: "memory");   // prev iter's 6 loads landed
    } else {
      asm volatile("s_waitcnt vmcnt(0)" ::: "memory");
    }
    SCB;
    __builtin_amdgcn_s_barrier();   // all waves' current-buffer loads landed
    SCB;

    half8 ah[2][2], al[2][2], bh[2][2];
#pragma unroll
    for (int i = 0; i < 2; ++i) {
      const int it = wm * 2 + i;
#pragma unroll
      for (int ks = 0; ks < 2; ++ks) {
        ah[i][ks] = *reinterpret_cast<const half8*>(
            ldsA + bo + ((((it * 2 + 0) * 2 + ks) * 2 + lh) * 32 + l31) * 8);
        al[i][ks] = *reinterpret_cast<const half8*>(
            ldsA + bo + ((((it * 2 + 1) * 2 + ks) * 2 + lh) * 32 + l31) * 8);
      }
    }
#pragma unroll
    for (int j = 0; j < 2; ++j) {
      const int jt = wn * 2 + j;
#pragma unroll
      for (int ks = 0; ks < 2; ++ks)
        bh[j][ks] = *reinterpret_cast<const half8*>(
            ldsB + bob + (((jt * 2 + ks) * 2 + lh) * 32 + l31) * 8);
    }
    asm volatile("s_waitcnt lgkmcnt(0)" ::: "memory");
    SCB;
    __builtin_amdgcn_s_setprio(1);
#pragma unroll
    for (int ks = 0; ks < 2; ++ks)
#pragma unroll
      for (int i = 0; i < 2; ++i)
#pragma unroll
        for (int j = 0; j < 2; ++j) {
          acc[i][j] = MFMA16(ah[i][ks], bh[j][ks], acc[i][j]);
          acc[i][j] = MFMA16(al[i][ks], bh[j][ks], acc[i][j]);
        }
    __builtin_amdgcn_s_setprio(0);
    SCB;
    __builtin_amdgcn_s_barrier();   // all waves done reading this buffer
    SCB;
  }

  // epilogue: scores + per-lane top-2 over this block's 128 codes
  float b1[2] = {-3.0e38f, -3.0e38f};
  float b2[2] = {-3.0e38f, -3.0e38f};
  int idx1[2] = {0, 0};
  const int code0 = ct * 128 + wm * 64;
#pragma unroll
  for (int i = 0; i < 2; ++i) {
    const float* ep = en2 + code0 + i * 32 + 4 * lh;
    const float4 e0 = *reinterpret_cast<const float4*>(ep);
    const float4 e1 = *reinterpret_cast<const float4*>(ep + 8);
    const float4 e2 = *reinterpret_cast<const float4*>(ep + 16);
    const float4 e3 = *reinterpret_cast<const float4*>(ep + 24);
    const float ev[16] = {e0.x, e0.y, e0.z, e0.w, e1.x, e1.y, e1.z, e1.w,
                          e2.x, e2.y, e2.z, e2.w, e3.x, e3.y, e3.z, e3.w};
#pragma unroll
    for (int reg = 0; reg < 16; ++reg) {
      const int code = code0 + i * 32 + (reg & 3) + 8 * (reg >> 2) + 4 * lh;
#pragma unroll
      for (int j = 0; j < 2; ++j) {
        const float v = acc[i][j][reg] - ev[reg];
        if (v > b1[j] || (v == b1[j] && code < idx1[j])) {
          b2[j] = b1[j]; b1[j] = v; idx1[j] = code;
        } else if (v > b2[j]) {
          b2[j] = v;
        }
      }
    }
  }

  // merge lane <-> lane^32 (same x-row, disjoint code subsets)
#pragma unroll
  for (int j = 0; j < 2; ++j) {
    const float o1 = __shfl_xor(b1[j], 32, 64);
    const int oi = __shfl_xor(idx1[j], 32, 64);
    const float o2 = __shfl_xor(b2[j], 32, 64);
    const bool win = (b1[j] > o1) || (b1[j] == o1 && idx1[j] < oi);
    const float lose1 = win ? o1 : b1[j];
    b1[j] = win ? b1[j] : o1;
    idx1[j] = win ? idx1[j] : oi;
    b2[j] = fmaxf(fmaxf(b2[j], o2), lose1);
  }

  // cross-wave (wm 0 vs 1) merge via LDS scratch
  float* scr = reinterpret_cast<float*>(ldsA);   // [2][128][3]
  __syncthreads();
  if (lane < 32) {
#pragma unroll
    for (int j = 0; j < 2; ++j) {
      const int rowl = wn * 64 + j * 32 + l31;
      const int base = (wm * 128 + rowl) * 3;
      scr[base + 0] = b1[j];
      scr[base + 1] = __int_as_float(idx1[j]);
      scr[base + 2] = b2[j];
    }
  }
  __syncthreads();
  if (tid < 128) {
    float v1 = scr[tid * 3 + 0];
    int ii = __float_as_int(scr[tid * 3 + 1]);
    float v2 = scr[tid * 3 + 2];
    const float o1 = scr[(128 + tid) * 3 + 0];
    const int oi = __float_as_int(scr[(128 + tid) * 3 + 1]);
    const float o2 = scr[(128 + tid) * 3 + 2];
    const bool win = (v1 > o1) || (v1 == o1 && ii < oi);
    const float lose1 = win ? o1 : v1;
    const float nb1 = win ? v1 : o1;
    const int ni = win ? ii : oi;
    const float nb2 = fmaxf(fmaxf(v2, o2), lose1);
    const int row = bx * 128 + tid;
    candV[(size_t)row * NSPLIT + ct] = nb1;
    candI[(size_t)row * NSPLIT + ct] = ni;
    cand2[(size_t)row * NSPLIT + ct] = nb2;
  }
}

// ---- merge splits -> index, margin; flag risky rows ----
__global__ void vq_reduce(const float* __restrict__ candV, const int* __restrict__ candI,
                          const float* __restrict__ cand2, int* __restrict__ ind,
                          int* __restrict__ cnt, int* __restrict__ risky,
                          unsigned long long* __restrict__ key) {
  const int row = blockIdx.x * blockDim.x + threadIdx.x;
  if (row >= M_ROWS) return;
  float b1 = candV[(size_t)row * NSPLIT];
  int i1 = candI[(size_t)row * NSPLIT];
  float b2 = cand2[(size_t)row * NSPLIT];
  for (int s = 1; s < NSPLIT; ++s) {
    const float v = candV[(size_t)row * NSPLIT + s];
    const int ii = candI[(size_t)row * NSPLIT + s];
    const float v2 = cand2[(size_t)row * NSPLIT + s];
    if (v > b1 || (v == b1 && ii < i1)) {
      b2 = fmaxf(b1, v2); b1 = v; i1 = ii;
    } else {
      b2 = fmaxf(b2, v);
    }
  }
  ind[row] = i1;
  if (b1 - b2 < TAU) {
    const int p = atomicAdd(cnt, 1);
    if (p < CAP) { risky[p] = row; key[row] = 0ull; }
  }
}

// ---- exact fp32 rescore of risky rows, striped over RSTRIDE block-columns ----
__global__ __launch_bounds__(256)
void vq_refine(const float* __restrict__ x, const float* __restrict__ cb,
               const float* __restrict__ en2, const int* __restrict__ cnt,
               const int* __restrict__ risky, unsigned long long* __restrict__ key) {
  __shared__ float cbs[16][256];
  __shared__ float xs[256];
  const int n0 = *cnt;
  const int n = n0 < CAP ? n0 : CAP;
  const int stripe = blockIdx.x;
  if (stripe >= n) return;
  const int tid = threadIdx.x;
  const int cBase = blockIdx.y * 16;
#pragma unroll
  for (int q = 0; q < 16; ++q) cbs[q][tid] = cb[(size_t)(cBase + q) * K_DIM + tid];
  const int sub = tid & 15;
  const int cl = tid >> 4;
  for (int t = stripe; t < n; t += RSTRIDE) {
    const int row = risky[t];
    __syncthreads();
    xs[tid] = x[(size_t)row * K_DIM + tid];
    __syncthreads();
    float s = 0.f;
#pragma unroll
    for (int k = 0; k < 16; ++k) s = fmaf(xs[sub * 16 + k], cbs[cl][sub * 16 + k], s);
    s += __shfl_xor(s, 1, 64); s += __shfl_xor(s, 2, 64);
    s += __shfl_xor(s, 4, 64); s += __shfl_xor(s, 8, 64);
    if (sub == 0) {
      const int code = cBase + cl;
      const float sc = s - en2[code];
      unsigned u = __float_as_uint(sc);
      u ^= (u >> 31) ? 0xFFFFFFFFu : 0x80000000u;
      const unsigned long long k64 =
          ((unsigned long long)u << 32) | (unsigned)(N_CODES - 1 - code);
      atomicMax(key + row, k64);
    }
  }
}

__global__ void vq_fix(const int* __restrict__ cnt, const int* __restrict__ risky,
                       const unsigned long long* __restrict__ key, int* __restrict__ ind) {
  const int i = blockIdx.x * blockDim.x + threadIdx.x;
  const int n = *cnt < CAP ? *cnt : CAP;
  if (i < n) {
    const int r = risky[i];
    ind[r] = N_CODES - 1 - (int)(unsigned)(key[r] & 0xFFFFFFFFull);
  }
}

// ---- gather z_q, write z_q_st + indices, partial loss sums ----
__global__ void vq_gather(const float* __restrict__ x, const float* __restrict__ cb,
                          const int* __restrict__ ind, float* __restrict__ zq,
                          float* __restrict__ idxf, float* __restrict__ partial) {
  __shared__ float red[256];
  const int g = blockIdx.x * 256 + threadIdx.x;
  const int row = g >> 6;
  const int c4 = g & 63;
  const int idx = ind[row];
  if (c4 == 0) idxf[row] = (float)idx;
  const float4 z = *reinterpret_cast<const float4*>(cb + (size_t)idx * K_DIM + c4 * 4);
  const float4 xv = *reinterpret_cast<const float4*>(x + (size_t)g * 4);
  *reinterpret_cast<float4*>(zq + (size_t)g * 4) = z;
  const float dx = z.x - xv.x, dy = z.y - xv.y, dz = z.z - xv.z, dw = z.w - xv.w;
  red[threadIdx.x] = dx * dx + dy * dy + dz * dz + dw * dw;
  __syncthreads();
  for (int o = 128; o > 0; o >>= 1) {
    if (threadIdx.x < o) red[threadIdx.x] += red[threadIdx.x + o];
    __syncthreads();
  }
  if (threadIdx.x == 0) partial[blockIdx.x] = red[0];
}

__global__ void vq_loss(const float* __restrict__ partial, float* __restrict__ out) {
  __shared__ float red[256];
  float s = 0.f;
  for (int i = threadIdx.x; i < 4096; i += 256) s += partial[i];
  red[threadIdx.x] = s;
  __syncthreads();
  for (int o = 128; o > 0; o >>= 1) {
    if (threadIdx.x < o) red[threadIdx.x] += red[threadIdx.x + o];
    __syncthreads();
  }
  if (threadIdx.x == 0) out[0] = 1.25f * red[0] / 4194304.0f;
}

extern "C" void kernel_launch(void* const* d_in, const int* in_sizes, int n_in,
                              void* d_out, int out_size, void* d_ws, size_t ws_size,
                              hipStream_t stream) {
  const float* x = (const float*)d_in[0];
  const float* cb = (const float*)d_in[1];
  float* out = (float*)d_out;
  float* zq = out;
  float* loss = out + 4194304;
  float* idxf = out + 4194305;

  char* w = (char*)d_ws;
  _Float16* Apack = (_Float16*)w;                      w += (size_t)N_CODES * K_DIM * 2 * 2;   // 8MB h+l
  _Float16* Bpack = (_Float16*)w;                      w += (size_t)M_ROWS * K_DIM * 2;        // 8MB h
  unsigned long long* key = (unsigned long long*)w;    w += (size_t)M_ROWS * 8;
  float* en2 = (float*)w;                              w += (size_t)N_CODES * 4;
  float* candV = (float*)w;                            w += (size_t)M_ROWS * NSPLIT * 4;
  float* cand2 = (float*)w;                            w += (size_t)M_ROWS * NSPLIT * 4;
  int* candI = (int*)w;                                w += (size_t)M_ROWS * NSPLIT * 4;
  int* ind = (int*)w;                                  w += (size_t)M_ROWS * 4;
  int* risky = (int*)w;                                w += (size_t)CAP * 4;
  int* cnt = (int*)w;                                  w += 64;
  float* part = (float*)w;                             w += 4096 * 4;

  pack_cb<<<(N_CODES * 32) / 256, 256, 0, stream>>>(cb, Apack);
  pack_x<<<(M_ROWS * 32) / 256, 256, 0, stream>>>(x, Bpack);
  enorm_k<<<N_CODES / 4, 256, 0, stream>>>(cb, en2, cnt);
  vq_dist<<<8192, 256, 0, stream>>>(Apack, Bpack, en2, candV, candI, cand2);
  vq_reduce<<<M_ROWS / 256, 256, 0, stream>>>(candV, candI, cand2, ind, cnt, risky, key);
  vq_refine<<<dim3(RSTRIDE, N_CODES / 16), 256, 0, stream>>>(x, cb, en2, cnt, risky, key);
  vq_fix<<<CAP / 256, 256, 0, stream>>>(cnt, risky, key, ind);
  vq_gather<<<4194304 / (256 * 4), 256, 0, stream>>>(x, cb, ind, zq, idxf, part);
  vq_loss<<<1, 256, 0, stream>>>(part, loss);
}